// Round 1
// baseline (867.698 us; speedup 1.0000x reference)
//
#include <hip/hip_runtime.h>
#include <cstddef>

// Problem sizes (fixed by the reference)
constexpr int Bn  = 4;
constexpr int Ln  = 2048;
constexpr int Dn  = 512;
constexpr int Hn  = 8;
constexpr int DKn = 64;
constexpr int Mtot = Bn * Ln;   // 8192 rows

// ---------------------------------------------------------------------------
// Kernel 1: fused QKV projection.  C[m][n] = sum_k X[m][k] * W[n][k] + b[n],
// written directly into head layout  Out[b][h][l][dk]  (b=m>>11, l=m&2047,
// h=blockIdx.y, dk = n&63).
// grid: (Mtot/64, Dn/64, 3)   block: 256
// ---------------------------------------------------------------------------
__global__ __launch_bounds__(256) void qkv_proj(
    const float* __restrict__ q, const float* __restrict__ k, const float* __restrict__ v,
    const float* __restrict__ wq, const float* __restrict__ wk, const float* __restrict__ wv,
    const float* __restrict__ bq, const float* __restrict__ bk, const float* __restrict__ bv,
    float* __restrict__ Qh, float* __restrict__ Kh, float* __restrict__ Vh)
{
    const int p = blockIdx.z;
    const float* X    = (p == 0) ? q  : (p == 1) ? k  : v;
    const float* W    = (p == 0) ? wq : (p == 1) ? wk : wv;
    const float* bias = (p == 0) ? bq : (p == 1) ? bk : bv;
    float*       O    = (p == 0) ? Qh : (p == 1) ? Kh : Vh;

    __shared__ float Xs[32][68];   // [kk][row]  transposed, stride 68 keeps 16B alignment
    __shared__ float Ws[32][68];   // [kk][col]

    const int tid = threadIdx.x;
    const int tx = tid & 15, ty = tid >> 4;
    const int m0 = blockIdx.x * 64;
    const int n0 = blockIdx.y * 64;

    float acc[4][4];
    #pragma unroll
    for (int i = 0; i < 4; ++i)
        #pragma unroll
        for (int j = 0; j < 4; ++j) acc[i][j] = 0.f;

    for (int k0 = 0; k0 < Dn; k0 += 32) {
        #pragma unroll
        for (int f = 0; f < 2; ++f) {
            int lin = tid + 256 * f;            // 0..511
            int r   = lin >> 3;                 // 0..63  (8 float4 per 32-float row)
            int c4  = lin & 7;
            float4 xv = *(const float4*)&X[(size_t)(m0 + r) * Dn + k0 + c4 * 4];
            float4 wv4 = *(const float4*)&W[(size_t)(n0 + r) * Dn + k0 + c4 * 4];
            Xs[c4*4+0][r] = xv.x; Xs[c4*4+1][r] = xv.y; Xs[c4*4+2][r] = xv.z; Xs[c4*4+3][r] = xv.w;
            Ws[c4*4+0][r] = wv4.x; Ws[c4*4+1][r] = wv4.y; Ws[c4*4+2][r] = wv4.z; Ws[c4*4+3][r] = wv4.w;
        }
        __syncthreads();
        #pragma unroll
        for (int kk = 0; kk < 32; ++kk) {
            float4 a = *(const float4*)&Xs[kk][ty * 4];
            float4 b = *(const float4*)&Ws[kk][tx * 4];
            float av[4] = {a.x, a.y, a.z, a.w};
            float bv2[4] = {b.x, b.y, b.z, b.w};
            #pragma unroll
            for (int i = 0; i < 4; ++i)
                #pragma unroll
                for (int j = 0; j < 4; ++j)
                    acc[i][j] += av[i] * bv2[j];
        }
        __syncthreads();
    }

    // write head layout: m0 multiple of 64, Ln multiple of 64 -> whole tile same batch
    const int bb = m0 >> 11;            // m0 / Ln
    const int h  = blockIdx.y;          // n0>>6
    #pragma unroll
    for (int i = 0; i < 4; ++i) {
        int l = (m0 & (Ln - 1)) + ty * 4 + i;
        float4 o;
        o.x = acc[i][0] + bias[h * DKn + tx * 4 + 0];
        o.y = acc[i][1] + bias[h * DKn + tx * 4 + 1];
        o.z = acc[i][2] + bias[h * DKn + tx * 4 + 2];
        o.w = acc[i][3] + bias[h * DKn + tx * 4 + 3];
        *(float4*)&O[(((size_t)bb * Hn + h) * Ln + l) * DKn + tx * 4] = o;
    }
}

// ---------------------------------------------------------------------------
// Kernel 2: flash attention, fp32.  64 q-rows per block, 32 k-cols per tile.
// Threads 16x16: each owns 4 q-rows (ty) x {2 score cols / 4 dk cols} (tx).
// grid: (Ln/64, Bn*Hn)   block: 256
// ---------------------------------------------------------------------------
__global__ __launch_bounds__(256) void attn_fp32(
    const float* __restrict__ Qh, const float* __restrict__ Kh, const float* __restrict__ Vh,
    const int* __restrict__ masks, float* __restrict__ Ctx)
{
    __shared__ float Qs[64][68];    // [dk][qrow]   transposed
    __shared__ float Ks[64][36];    // [dk][kcol]   transposed
    __shared__ float Vs[32][64];    // [kcol][dk]   row-major
    __shared__ float Ps[32][68];    // [kcol][qrow] transposed
    __shared__ float maskS[32];

    const int tid = threadIdx.x;
    const int tx = tid & 15, ty = tid >> 4;
    const int bh = blockIdx.y;
    const int bb = bh >> 3;
    const int h  = bh & 7;
    const int q0 = blockIdx.x * 64;

    const float* Qp = Qh + (size_t)bh * Ln * DKn;
    const float* Kp = Kh + (size_t)bh * Ln * DKn;
    const float* Vp = Vh + (size_t)bh * Ln * DKn;
    const int*   mp = masks + bb * Ln;

    // load Q tile (64 x 64) transposed into Qs
    #pragma unroll
    for (int f = 0; f < 4; ++f) {
        int lin = tid + 256 * f;            // 0..1023
        int r   = lin >> 4;                 // 0..63
        int c4  = lin & 15;
        float4 x = *(const float4*)&Qp[(size_t)(q0 + r) * DKn + c4 * 4];
        Qs[c4*4+0][r] = x.x; Qs[c4*4+1][r] = x.y; Qs[c4*4+2][r] = x.z; Qs[c4*4+3][r] = x.w;
    }

    float m_run[4], l_run[4], acc[4][4];
    #pragma unroll
    for (int i = 0; i < 4; ++i) {
        m_run[i] = -1e30f; l_run[i] = 0.f;
        #pragma unroll
        for (int j = 0; j < 4; ++j) acc[i][j] = 0.f;
    }

    for (int k0 = 0; k0 < Ln; k0 += 32) {
        __syncthreads();   // prev PV done before overwriting Ks/Vs/Ps
        #pragma unroll
        for (int f = 0; f < 2; ++f) {
            int lin = tid + 256 * f;        // 0..511
            int r   = lin >> 4;             // 0..31
            int c4  = lin & 15;
            float4 kx = *(const float4*)&Kp[(size_t)(k0 + r) * DKn + c4 * 4];
            Ks[c4*4+0][r] = kx.x; Ks[c4*4+1][r] = kx.y; Ks[c4*4+2][r] = kx.z; Ks[c4*4+3][r] = kx.w;
            float4 vx = *(const float4*)&Vp[(size_t)(k0 + r) * DKn + c4 * 4];
            *(float4*)&Vs[r][c4 * 4] = vx;
        }
        if (tid < 32) maskS[tid] = (mp[k0 + tid] == 0) ? 0.f : 1.f;
        __syncthreads();

        // S = Q K^T * 0.125  (4 rows x 2 cols per thread)
        float s[4][2];
        #pragma unroll
        for (int i = 0; i < 4; ++i) { s[i][0] = 0.f; s[i][1] = 0.f; }
        #pragma unroll 8
        for (int kk = 0; kk < 64; ++kk) {
            float4 a = *(const float4*)&Qs[kk][ty * 4];
            float2 b = *(const float2*)&Ks[kk][tx * 2];
            float av[4] = {a.x, a.y, a.z, a.w};
            s[0][0] += av[0] * b.x;  s[0][1] += av[0] * b.y;
            s[1][0] += av[1] * b.x;  s[1][1] += av[1] * b.y;
            s[2][0] += av[2] * b.x;  s[2][1] += av[2] * b.y;
            s[3][0] += av[3] * b.x;  s[3][1] += av[3] * b.y;
        }
        const float mk0 = maskS[tx * 2 + 0];
        const float mk1 = maskS[tx * 2 + 1];
        #pragma unroll
        for (int i = 0; i < 4; ++i) {
            s[i][0] = (mk0 != 0.f) ? s[i][0] * 0.125f : -1e30f;
            s[i][1] = (mk1 != 0.f) ? s[i][1] * 0.125f : -1e30f;
        }

        // online softmax (row spread over 16 tx lanes)
        #pragma unroll
        for (int i = 0; i < 4; ++i) {
            float rmax = fmaxf(s[i][0], s[i][1]);
            #pragma unroll
            for (int off = 1; off < 16; off <<= 1)
                rmax = fmaxf(rmax, __shfl_xor(rmax, off, 64));
            float mnew = fmaxf(m_run[i], rmax);
            float fac  = __expf(m_run[i] - mnew);
            s[i][0] = __expf(s[i][0] - mnew);
            s[i][1] = __expf(s[i][1] - mnew);
            float rsum = s[i][0] + s[i][1];
            #pragma unroll
            for (int off = 1; off < 16; off <<= 1)
                rsum += __shfl_xor(rsum, off, 64);
            l_run[i] = l_run[i] * fac + rsum;
            m_run[i] = mnew;
            acc[i][0] *= fac; acc[i][1] *= fac; acc[i][2] *= fac; acc[i][3] *= fac;
            // write P transposed: Ps[kcol][qrow]
            Ps[tx * 2 + 0][ty * 4 + i] = s[i][0];
            Ps[tx * 2 + 1][ty * 4 + i] = s[i][1];
        }
        __syncthreads();

        // O += P V   (4 rows x 4 dk per thread)
        #pragma unroll 8
        for (int kc = 0; kc < 32; ++kc) {
            float4 a = *(const float4*)&Ps[kc][ty * 4];
            float4 b = *(const float4*)&Vs[kc][tx * 4];
            float av[4] = {a.x, a.y, a.z, a.w};
            float bv2[4] = {b.x, b.y, b.z, b.w};
            #pragma unroll
            for (int i = 0; i < 4; ++i)
                #pragma unroll
                for (int j = 0; j < 4; ++j)
                    acc[i][j] += av[i] * bv2[j];
        }
    }

    // epilogue: normalize, write concat layout Ctx[b*Ln+l][h*DKn+dk]
    #pragma unroll
    for (int i = 0; i < 4; ++i) {
        float inv = 1.0f / l_run[i];
        int l = q0 + ty * 4 + i;
        float4 o;
        o.x = acc[i][0] * inv; o.y = acc[i][1] * inv;
        o.z = acc[i][2] * inv; o.w = acc[i][3] * inv;
        *(float4*)&Ctx[((size_t)bb * Ln + l) * Dn + h * DKn + tx * 4] = o;
    }
}

// ---------------------------------------------------------------------------
// Kernel 3: output projection.  Out[m][n] = sum_k Ctx[m][k] * Wo[n][k] + bo[n]
// grid: (Mtot/64, Dn/64)   block: 256
// ---------------------------------------------------------------------------
__global__ __launch_bounds__(256) void out_proj(
    const float* __restrict__ X, const float* __restrict__ W,
    const float* __restrict__ bias, float* __restrict__ Out)
{
    __shared__ float Xs[32][68];
    __shared__ float Ws[32][68];

    const int tid = threadIdx.x;
    const int tx = tid & 15, ty = tid >> 4;
    const int m0 = blockIdx.x * 64;
    const int n0 = blockIdx.y * 64;

    float acc[4][4];
    #pragma unroll
    for (int i = 0; i < 4; ++i)
        #pragma unroll
        for (int j = 0; j < 4; ++j) acc[i][j] = 0.f;

    for (int k0 = 0; k0 < Dn; k0 += 32) {
        #pragma unroll
        for (int f = 0; f < 2; ++f) {
            int lin = tid + 256 * f;
            int r   = lin >> 3;
            int c4  = lin & 7;
            float4 xv = *(const float4*)&X[(size_t)(m0 + r) * Dn + k0 + c4 * 4];
            float4 wv4 = *(const float4*)&W[(size_t)(n0 + r) * Dn + k0 + c4 * 4];
            Xs[c4*4+0][r] = xv.x; Xs[c4*4+1][r] = xv.y; Xs[c4*4+2][r] = xv.z; Xs[c4*4+3][r] = xv.w;
            Ws[c4*4+0][r] = wv4.x; Ws[c4*4+1][r] = wv4.y; Ws[c4*4+2][r] = wv4.z; Ws[c4*4+3][r] = wv4.w;
        }
        __syncthreads();
        #pragma unroll
        for (int kk = 0; kk < 32; ++kk) {
            float4 a = *(const float4*)&Xs[kk][ty * 4];
            float4 b = *(const float4*)&Ws[kk][tx * 4];
            float av[4] = {a.x, a.y, a.z, a.w};
            float bv2[4] = {b.x, b.y, b.z, b.w};
            #pragma unroll
            for (int i = 0; i < 4; ++i)
                #pragma unroll
                for (int j = 0; j < 4; ++j)
                    acc[i][j] += av[i] * bv2[j];
        }
        __syncthreads();
    }

    #pragma unroll
    for (int i = 0; i < 4; ++i) {
        int m = m0 + ty * 4 + i;
        float4 o;
        o.x = acc[i][0] + bias[n0 + tx * 4 + 0];
        o.y = acc[i][1] + bias[n0 + tx * 4 + 1];
        o.z = acc[i][2] + bias[n0 + tx * 4 + 2];
        o.w = acc[i][3] + bias[n0 + tx * 4 + 3];
        *(float4*)&Out[(size_t)m * Dn + n0 + tx * 4] = o;
    }
}

// ---------------------------------------------------------------------------
extern "C" void kernel_launch(void* const* d_in, const int* in_sizes, int n_in,
                              void* d_out, int out_size, void* d_ws, size_t ws_size,
                              hipStream_t stream)
{
    const float* q    = (const float*)d_in[0];
    const float* k    = (const float*)d_in[1];
    const float* v    = (const float*)d_in[2];
    const int*   mks  = (const int*)  d_in[3];
    const float* wq_w = (const float*)d_in[4];
    const float* wq_b = (const float*)d_in[5];
    const float* wk_w = (const float*)d_in[6];
    const float* wk_b = (const float*)d_in[7];
    const float* wv_w = (const float*)d_in[8];
    const float* wv_b = (const float*)d_in[9];
    const float* wo_w = (const float*)d_in[10];
    const float* wo_b = (const float*)d_in[11];
    float* out = (float*)d_out;

    const size_t headElems = (size_t)Bn * Hn * Ln * DKn;   // 4,194,304
    float* ws  = (float*)d_ws;
    float* Qh  = ws;
    float* Kh  = ws + headElems;
    float* Vh  = ws + 2 * headElems;
    float* Ctx = ws + 3 * headElems;

    qkv_proj<<<dim3(Mtot / 64, Dn / 64, 3), 256, 0, stream>>>(
        q, k, v, wq_w, wk_w, wv_w, wq_b, wk_b, wv_b, Qh, Kh, Vh);

    attn_fp32<<<dim3(Ln / 64, Bn * Hn), 256, 0, stream>>>(Qh, Kh, Vh, mks, Ctx);

    out_proj<<<dim3(Mtot / 64, Dn / 64), 256, 0, stream>>>(Ctx, wo_w, wo_b, out);
}

// Round 2
// 166.738 us; speedup vs baseline: 5.2039x; 5.2039x over previous
//
#include <hip/hip_runtime.h>
#include <cstddef>

typedef __attribute__((ext_vector_type(8))) short bf16x8;
typedef __attribute__((ext_vector_type(4))) short bf16x4;
typedef __attribute__((ext_vector_type(4))) float f32x4;

constexpr int Bn = 4, Ln = 2048, Dn = 512, Hn = 8, DKn = 64, Mtot = 8192;

__device__ inline short f2bf(float x) {
    union { float f; unsigned u; } v; v.f = x;
    unsigned r = v.u + 0x7fffu + ((v.u >> 16) & 1u);   // RNE
    return (short)(r >> 16);
}

// ---------------------------------------------------------------------------
// Kernel 1: QKV projection, bf16 MFMA.  C = X @ W^T + b.
// Outputs: Q,K as bf16 [b][h][l][dk];  V as bf16 TRANSPOSED [b][h][dk][l].
// Tile 128x128, BK=64, 4 waves (2x2), each wave 64x64 (4x4 frags 16x16x32).
// grid (Mtot/128, Dn/128, 3), block 256.
// ---------------------------------------------------------------------------
__global__ __launch_bounds__(256) void qkv_proj_mfma(
    const float* __restrict__ q, const float* __restrict__ k, const float* __restrict__ v,
    const float* __restrict__ wq, const float* __restrict__ wk, const float* __restrict__ wv,
    const float* __restrict__ bq, const float* __restrict__ bk, const float* __restrict__ bv,
    short* __restrict__ Qh, short* __restrict__ Kh, short* __restrict__ Vt)
{
    const int p = blockIdx.z;
    const float* X    = (p == 0) ? q  : (p == 1) ? k  : v;
    const float* W    = (p == 0) ? wq : (p == 1) ? wk : wv;
    const float* bias = (p == 0) ? bq : (p == 1) ? bk : bv;
    short*       O    = (p == 0) ? Qh : (p == 1) ? Kh : Vt;

    __shared__ short As[128 * 72];   // [row][k] bf16, pad 72 (144B rows, 16B-aligned)
    __shared__ short Bs[128 * 72];

    const int tid  = threadIdx.x;
    const int lane = tid & 63, w = tid >> 6;
    const int wr = w >> 1, wc = w & 1;
    const int l16 = lane & 15, g = lane >> 4;
    const int m0 = blockIdx.x * 128, n0 = blockIdx.y * 128;

    f32x4 acc[4][4];
    #pragma unroll
    for (int i = 0; i < 4; ++i)
        #pragma unroll
        for (int j = 0; j < 4; ++j)
            acc[i][j] = (f32x4){0.f, 0.f, 0.f, 0.f};

    for (int k0 = 0; k0 < Dn; k0 += 64) {
        // stage: 128x64 fp32 -> bf16, A and B tiles (8 float4 each per thread)
        #pragma unroll
        for (int f = 0; f < 8; ++f) {
            int lin = tid + 256 * f;     // 0..2047
            int row = lin >> 4, c4 = lin & 15;
            float4 xv = *(const float4*)&X[(size_t)(m0 + row) * Dn + k0 + c4 * 4];
            bf16x4 xb; xb[0] = f2bf(xv.x); xb[1] = f2bf(xv.y); xb[2] = f2bf(xv.z); xb[3] = f2bf(xv.w);
            *(bf16x4*)&As[row * 72 + c4 * 4] = xb;
            float4 wv4 = *(const float4*)&W[(size_t)(n0 + row) * Dn + k0 + c4 * 4];
            bf16x4 wb; wb[0] = f2bf(wv4.x); wb[1] = f2bf(wv4.y); wb[2] = f2bf(wv4.z); wb[3] = f2bf(wv4.w);
            *(bf16x4*)&Bs[row * 72 + c4 * 4] = wb;
        }
        __syncthreads();

        bf16x8 af[4][2], bf[4][2];
        #pragma unroll
        for (int i = 0; i < 4; ++i)
            #pragma unroll
            for (int c = 0; c < 2; ++c)
                af[i][c] = *(const bf16x8*)&As[(wr * 64 + i * 16 + l16) * 72 + c * 32 + g * 8];
        #pragma unroll
        for (int j = 0; j < 4; ++j)
            #pragma unroll
            for (int c = 0; c < 2; ++c)
                bf[j][c] = *(const bf16x8*)&Bs[(wc * 64 + j * 16 + l16) * 72 + c * 32 + g * 8];

        #pragma unroll
        for (int i = 0; i < 4; ++i)
            #pragma unroll
            for (int j = 0; j < 4; ++j) {
                acc[i][j] = __builtin_amdgcn_mfma_f32_16x16x32_bf16(af[i][0], bf[j][0], acc[i][j], 0, 0, 0);
                acc[i][j] = __builtin_amdgcn_mfma_f32_16x16x32_bf16(af[i][1], bf[j][1], acc[i][j], 0, 0, 0);
            }
        __syncthreads();
    }

    // epilogue: D-frag row=(g*4+r), col=l16
    const int bb = m0 >> 11;     // batch (Ln=2048, BM=128 divides)
    #pragma unroll
    for (int i = 0; i < 4; ++i) {
        #pragma unroll
        for (int j = 0; j < 4; ++j) {
            int n  = n0 + wc * 64 + j * 16 + l16;
            int h  = n >> 6, dk = n & 63;
            float bval = bias[n];
            #pragma unroll
            for (int r = 0; r < 4; ++r) {
                int m  = m0 + wr * 64 + i * 16 + g * 4 + r;
                int lq = m & (Ln - 1);
                short val = f2bf(acc[i][j][r] + bval);
                if (p < 2)
                    O[(((size_t)bb * Hn + h) * Ln + lq) * DKn + dk] = val;       // [bh][l][dk]
                else
                    O[(((size_t)bb * Hn + h) * DKn + dk) * Ln + lq] = val;       // [bh][dk][l]
            }
        }
    }
}

// ---------------------------------------------------------------------------
// Kernel 2: flash attention, bf16 MFMA. 64 q-rows/block (4 waves x 16),
// KV-tile 64. K LDS [kc][dk] swizzled; V^T LDS [dk][kc] swizzled;
// per-wave P LDS [16 q][64 kc] swizzled.
// grid (Ln/64, Bn*Hn), block 256.
// ---------------------------------------------------------------------------
__global__ __launch_bounds__(256) void attn_mfma(
    const short* __restrict__ Qh, const short* __restrict__ Kh, const short* __restrict__ Vt,
    const int* __restrict__ masks, short* __restrict__ Ctx)
{
    __shared__ short Ks[64 * 64];
    __shared__ short Vs[64 * 64];
    __shared__ short Pl[4][16 * 64];
    __shared__ float maskAdd[64];

    const int tid  = threadIdx.x;
    const int lane = tid & 63, w = tid >> 6;
    const int l16 = lane & 15, g = lane >> 4;
    const int bh = blockIdx.y;
    const int bb = bh >> 3, h = bh & 7;
    const int q0 = blockIdx.x * 64;

    const short* Qp = Qh + (size_t)bh * Ln * DKn;
    const short* Kp = Kh + (size_t)bh * Ln * DKn;
    const short* Vp = Vt + (size_t)bh * DKn * Ln;
    const int*   mp = masks + bb * Ln;

    // Q fragments in registers (wave w owns q-rows q0+w*16 .. +15)
    bf16x8 qf0 = *(const bf16x8*)&Qp[(size_t)(q0 + w * 16 + l16) * DKn + g * 8];
    bf16x8 qf1 = *(const bf16x8*)&Qp[(size_t)(q0 + w * 16 + l16) * DKn + 32 + g * 8];

    f32x4 oacc[4];
    #pragma unroll
    for (int d = 0; d < 4; ++d) oacc[d] = (f32x4){0.f, 0.f, 0.f, 0.f};
    float m_run[4], l_run[4];
    #pragma unroll
    for (int r = 0; r < 4; ++r) { m_run[r] = -1e30f; l_run[r] = 0.f; }

    for (int t = 0; t < Ln / 64; ++t) {
        const int k0 = t * 64;
        __syncthreads();   // all waves done reading Ks/Vs of prev tile
        #pragma unroll
        for (int f = 0; f < 2; ++f) {
            int lin = tid + 256 * f;            // 0..511
            int row = lin >> 3, c8 = lin & 7;   // 64 rows x 8 chunks of 8 bf16
            bf16x8 kv = *(const bf16x8*)&Kp[(size_t)(k0 + row) * DKn + c8 * 8];
            *(bf16x8*)&Ks[row * 64 + ((c8 * 8) ^ ((row & 7) << 3))] = kv;
            bf16x8 vv = *(const bf16x8*)&Vp[(size_t)row * Ln + k0 + c8 * 8];
            *(bf16x8*)&Vs[row * 64 + ((c8 * 8) ^ ((row & 7) << 3))] = vv;
        }
        if (tid < 64) maskAdd[tid] = (mp[k0 + tid] == 0) ? -1e30f : 0.f;
        __syncthreads();

        // ---- S = Q K^T : 4 kt tiles of 16 kc, K-dim 64 = 2 MFMA each
        f32x4 sv[4];
        #pragma unroll
        for (int kt = 0; kt < 4; ++kt) {
            int row = kt * 16 + l16;
            bf16x8 kf0 = *(const bf16x8*)&Ks[row * 64 + ((g * 8) ^ ((row & 7) << 3))];
            bf16x8 kf1 = *(const bf16x8*)&Ks[row * 64 + ((32 + g * 8) ^ ((row & 7) << 3))];
            f32x4 z = (f32x4){0.f, 0.f, 0.f, 0.f};
            z = __builtin_amdgcn_mfma_f32_16x16x32_bf16(qf0, kf0, z, 0, 0, 0);
            z = __builtin_amdgcn_mfma_f32_16x16x32_bf16(qf1, kf1, z, 0, 0, 0);
            sv[kt] = z;
        }
        float mk[4];
        #pragma unroll
        for (int kt = 0; kt < 4; ++kt) mk[kt] = maskAdd[kt * 16 + l16];

        float s[4][4];   // [r][kt]
        #pragma unroll
        for (int kt = 0; kt < 4; ++kt)
            #pragma unroll
            for (int r = 0; r < 4; ++r)
                s[r][kt] = sv[kt][r] * 0.125f + mk[kt];

        // ---- online softmax (rows live in 16-lane groups)
        float fac[4];
        #pragma unroll
        for (int r = 0; r < 4; ++r) {
            float mt = fmaxf(fmaxf(s[r][0], s[r][1]), fmaxf(s[r][2], s[r][3]));
            #pragma unroll
            for (int off = 1; off < 16; off <<= 1)
                mt = fmaxf(mt, __shfl_xor(mt, off));
            float mnew = fmaxf(m_run[r], mt);
            fac[r] = __expf(m_run[r] - mnew);
            m_run[r] = mnew;
            float rs = 0.f;
            #pragma unroll
            for (int kt = 0; kt < 4; ++kt) { s[r][kt] = __expf(s[r][kt] - mnew); rs += s[r][kt]; }
            #pragma unroll
            for (int off = 1; off < 16; off <<= 1)
                rs += __shfl_xor(rs, off);
            l_run[r] = l_run[r] * fac[r] + rs;
        }
        #pragma unroll
        for (int d = 0; d < 4; ++d)
            #pragma unroll
            for (int r = 0; r < 4; ++r)
                oacc[d][r] *= fac[r];

        // ---- P -> per-wave LDS (bf16, A-frag layout), swizzled
        #pragma unroll
        for (int r = 0; r < 4; ++r) {
            int prow = g * 4 + r;
            #pragma unroll
            for (int kt = 0; kt < 4; ++kt)
                Pl[w][prow * 64 + ((kt * 16 + l16) ^ ((prow & 7) << 3))] = f2bf(s[r][kt]);
        }
        // same-wave LDS write->read is in-order; no barrier needed (Pl is wave-private)

        // ---- O += P V  (V^T rows = dk, K-contiguous)
        #pragma unroll
        for (int c = 0; c < 2; ++c) {
            int prow = l16;
            bf16x8 pf = *(const bf16x8*)&Pl[w][prow * 64 + ((c * 32 + g * 8) ^ ((prow & 7) << 3))];
            #pragma unroll
            for (int d = 0; d < 4; ++d) {
                int vrow = d * 16 + l16;
                bf16x8 vf = *(const bf16x8*)&Vs[vrow * 64 + ((c * 32 + g * 8) ^ ((vrow & 7) << 3))];
                oacc[d] = __builtin_amdgcn_mfma_f32_16x16x32_bf16(pf, vf, oacc[d], 0, 0, 0);
            }
        }
    }

    // epilogue: normalize, write Ctx bf16 [b*Ln+l][h*64+dk]
    #pragma unroll
    for (int r = 0; r < 4; ++r) {
        float inv = 1.0f / l_run[r];
        size_t mrow = (size_t)bb * Ln + q0 + w * 16 + g * 4 + r;
        #pragma unroll
        for (int d = 0; d < 4; ++d)
            Ctx[mrow * Dn + h * 64 + d * 16 + l16] = f2bf(oacc[d][r] * inv);
    }
}

// ---------------------------------------------------------------------------
// Kernel 3: output projection, bf16 MFMA. A = Ctx bf16, B = Wo fp32->bf16.
// Out fp32 + bias. Tile 128x128, BK=64. grid (Mtot/128, Dn/128), block 256.
// ---------------------------------------------------------------------------
__global__ __launch_bounds__(256) void out_proj_mfma(
    const short* __restrict__ Ctx, const float* __restrict__ W,
    const float* __restrict__ bias, float* __restrict__ Out)
{
    __shared__ short As[128 * 72];
    __shared__ short Bs[128 * 72];

    const int tid  = threadIdx.x;
    const int lane = tid & 63, w = tid >> 6;
    const int wr = w >> 1, wc = w & 1;
    const int l16 = lane & 15, g = lane >> 4;
    const int m0 = blockIdx.x * 128, n0 = blockIdx.y * 128;

    f32x4 acc[4][4];
    #pragma unroll
    for (int i = 0; i < 4; ++i)
        #pragma unroll
        for (int j = 0; j < 4; ++j)
            acc[i][j] = (f32x4){0.f, 0.f, 0.f, 0.f};

    for (int k0 = 0; k0 < Dn; k0 += 64) {
        #pragma unroll
        for (int f = 0; f < 4; ++f) {           // A: bf16 direct, 128x64 = 1024 chunks
            int lin = tid + 256 * f;
            int row = lin >> 3, c8 = lin & 7;
            bf16x8 av = *(const bf16x8*)&Ctx[(size_t)(m0 + row) * Dn + k0 + c8 * 8];
            *(bf16x8*)&As[row * 72 + c8 * 8] = av;
        }
        #pragma unroll
        for (int f = 0; f < 8; ++f) {           // B: fp32 -> bf16
            int lin = tid + 256 * f;
            int row = lin >> 4, c4 = lin & 15;
            float4 wv4 = *(const float4*)&W[(size_t)(n0 + row) * Dn + k0 + c4 * 4];
            bf16x4 wb; wb[0] = f2bf(wv4.x); wb[1] = f2bf(wv4.y); wb[2] = f2bf(wv4.z); wb[3] = f2bf(wv4.w);
            *(bf16x4*)&Bs[row * 72 + c4 * 4] = wb;
        }
        __syncthreads();

        bf16x8 af[4][2], bf[4][2];
        #pragma unroll
        for (int i = 0; i < 4; ++i)
            #pragma unroll
            for (int c = 0; c < 2; ++c)
                af[i][c] = *(const bf16x8*)&As[(wr * 64 + i * 16 + l16) * 72 + c * 32 + g * 8];
        #pragma unroll
        for (int j = 0; j < 4; ++j)
            #pragma unroll
            for (int c = 0; c < 2; ++c)
                bf[j][c] = *(const bf16x8*)&Bs[(wc * 64 + j * 16 + l16) * 72 + c * 32 + g * 8];

        #pragma unroll
        for (int i = 0; i < 4; ++i)
            #pragma unroll
            for (int j = 0; j < 4; ++j) {
                acc[i][j] = __builtin_amdgcn_mfma_f32_16x16x32_bf16(af[i][0], bf[j][0], acc[i][j], 0, 0, 0);
                acc[i][j] = __builtin_amdgcn_mfma_f32_16x16x32_bf16(af[i][1], bf[j][1], acc[i][j], 0, 0, 0);
            }
        __syncthreads();
    }

    #pragma unroll
    for (int i = 0; i < 4; ++i) {
        #pragma unroll
        for (int j = 0; j < 4; ++j) {
            int n = n0 + wc * 64 + j * 16 + l16;
            float bval = bias[n];
            #pragma unroll
            for (int r = 0; r < 4; ++r) {
                int m = m0 + wr * 64 + i * 16 + g * 4 + r;
                Out[(size_t)m * Dn + n] = acc[i][j][r] + bval;
            }
        }
    }
}

// ---------------------------------------------------------------------------
extern "C" void kernel_launch(void* const* d_in, const int* in_sizes, int n_in,
                              void* d_out, int out_size, void* d_ws, size_t ws_size,
                              hipStream_t stream)
{
    (void)in_sizes; (void)n_in; (void)out_size; (void)ws_size;
    const float* q    = (const float*)d_in[0];
    const float* k    = (const float*)d_in[1];
    const float* v    = (const float*)d_in[2];
    const int*   mks  = (const int*)  d_in[3];
    const float* wq_w = (const float*)d_in[4];
    const float* wq_b = (const float*)d_in[5];
    const float* wk_w = (const float*)d_in[6];
    const float* wk_b = (const float*)d_in[7];
    const float* wv_w = (const float*)d_in[8];
    const float* wv_b = (const float*)d_in[9];
    const float* wo_w = (const float*)d_in[10];
    const float* wo_b = (const float*)d_in[11];
    float* out = (float*)d_out;

    const size_t headElems = (size_t)Bn * Hn * Ln * DKn;   // 4,194,304
    short* ws  = (short*)d_ws;
    short* Qh  = ws;
    short* Kh  = ws + headElems;
    short* Vt  = ws + 2 * headElems;
    short* Ctx = ws + 3 * headElems;

    qkv_proj_mfma<<<dim3(Mtot / 128, Dn / 128, 3), 256, 0, stream>>>(
        q, k, v, wq_w, wk_w, wv_w, wq_b, wk_b, wv_b, Qh, Kh, Vt);

    attn_mfma<<<dim3(Ln / 64, Bn * Hn), 256, 0, stream>>>(Qh, Kh, Vt, mks, Ctx);

    out_proj_mfma<<<dim3(Mtot / 128, Dn / 128), 256, 0, stream>>>(Ctx, wo_w, wo_b, out);
}

// Round 3
// 166.662 us; speedup vs baseline: 5.2063x; 1.0005x over previous
//
#include <hip/hip_runtime.h>
#include <hip/hip_bf16.h>
#include <cstddef>

typedef __attribute__((ext_vector_type(8))) short bf16x8;
typedef __attribute__((ext_vector_type(4))) short bf16x4;
typedef __attribute__((ext_vector_type(4))) float f32x4;

constexpr int Bn = 4, Ln = 2048, Dn = 512, Hn = 8, DKn = 64, Mtot = 8192;
// 1/sqrt(DK) * log2(e): softmax computed in exp2 domain
constexpr float QSCALE = 0.125f * 1.44269504088896341f;

__device__ inline short f2bf(float x) {
    __hip_bfloat16 h = __float2bfloat16(x);   // RNE, hardware cvt
    short s; __builtin_memcpy(&s, &h, 2); return s;
}
__device__ inline unsigned pkbf(float lo, float hi) {
    unsigned a = (unsigned short)f2bf(lo);
    unsigned b = (unsigned short)f2bf(hi);
    return a | (b << 16);
}

// ---------------------------------------------------------------------------
// Kernel 1: QKV projection, bf16 MFMA.  C = X @ W^T + b.
// Q output pre-scaled by QSCALE.  Q,K: bf16 [b][h][l][dk]; V: bf16 [b][h][dk][l].
// Tile 128x128, BK=64, 4 waves (2x2). grid (Mtot/128, Dn/128, 3), block 256.
// ---------------------------------------------------------------------------
__global__ __launch_bounds__(256) void qkv_proj_mfma(
    const float* __restrict__ q, const float* __restrict__ k, const float* __restrict__ v,
    const float* __restrict__ wq, const float* __restrict__ wk, const float* __restrict__ wv,
    const float* __restrict__ bq, const float* __restrict__ bk, const float* __restrict__ bv,
    short* __restrict__ Qh, short* __restrict__ Kh, short* __restrict__ Vt)
{
    const int p = blockIdx.z;
    const float* X    = (p == 0) ? q  : (p == 1) ? k  : v;
    const float* W    = (p == 0) ? wq : (p == 1) ? wk : wv;
    const float* bias = (p == 0) ? bq : (p == 1) ? bk : bv;
    short*       O    = (p == 0) ? Qh : (p == 1) ? Kh : Vt;
    const float scl   = (p == 0) ? QSCALE : 1.0f;

    __shared__ short As[128 * 72];
    __shared__ short Bs[128 * 72];

    const int tid  = threadIdx.x;
    const int lane = tid & 63, w = tid >> 6;
    const int wr = w >> 1, wc = w & 1;
    const int l16 = lane & 15, g = lane >> 4;
    const int m0 = blockIdx.x * 128, n0 = blockIdx.y * 128;

    f32x4 acc[4][4];
    #pragma unroll
    for (int i = 0; i < 4; ++i)
        #pragma unroll
        for (int j = 0; j < 4; ++j)
            acc[i][j] = (f32x4){0.f, 0.f, 0.f, 0.f};

    for (int k0 = 0; k0 < Dn; k0 += 64) {
        #pragma unroll
        for (int f = 0; f < 8; ++f) {
            int lin = tid + 256 * f;
            int row = lin >> 4, c4 = lin & 15;
            float4 xv = *(const float4*)&X[(size_t)(m0 + row) * Dn + k0 + c4 * 4];
            bf16x4 xb; xb[0] = f2bf(xv.x); xb[1] = f2bf(xv.y); xb[2] = f2bf(xv.z); xb[3] = f2bf(xv.w);
            *(bf16x4*)&As[row * 72 + c4 * 4] = xb;
            float4 wv4 = *(const float4*)&W[(size_t)(n0 + row) * Dn + k0 + c4 * 4];
            bf16x4 wb; wb[0] = f2bf(wv4.x); wb[1] = f2bf(wv4.y); wb[2] = f2bf(wv4.z); wb[3] = f2bf(wv4.w);
            *(bf16x4*)&Bs[row * 72 + c4 * 4] = wb;
        }
        __syncthreads();

        bf16x8 af[4][2], bfv[4][2];
        #pragma unroll
        for (int i = 0; i < 4; ++i)
            #pragma unroll
            for (int c = 0; c < 2; ++c)
                af[i][c] = *(const bf16x8*)&As[(wr * 64 + i * 16 + l16) * 72 + c * 32 + g * 8];
        #pragma unroll
        for (int j = 0; j < 4; ++j)
            #pragma unroll
            for (int c = 0; c < 2; ++c)
                bfv[j][c] = *(const bf16x8*)&Bs[(wc * 64 + j * 16 + l16) * 72 + c * 32 + g * 8];

        #pragma unroll
        for (int i = 0; i < 4; ++i)
            #pragma unroll
            for (int j = 0; j < 4; ++j) {
                acc[i][j] = __builtin_amdgcn_mfma_f32_16x16x32_bf16(af[i][0], bfv[j][0], acc[i][j], 0, 0, 0);
                acc[i][j] = __builtin_amdgcn_mfma_f32_16x16x32_bf16(af[i][1], bfv[j][1], acc[i][j], 0, 0, 0);
            }
        __syncthreads();
    }

    const int bb = m0 >> 11;
    #pragma unroll
    for (int i = 0; i < 4; ++i) {
        #pragma unroll
        for (int j = 0; j < 4; ++j) {
            int n  = n0 + wc * 64 + j * 16 + l16;
            int h  = n >> 6, dk = n & 63;
            float bval = bias[n];
            #pragma unroll
            for (int r = 0; r < 4; ++r) {
                int m  = m0 + wr * 64 + i * 16 + g * 4 + r;
                int lq = m & (Ln - 1);
                short val = f2bf((acc[i][j][r] + bval) * scl);
                if (p < 2)
                    O[(((size_t)bb * Hn + h) * Ln + lq) * DKn + dk] = val;
                else
                    O[(((size_t)bb * Hn + h) * DKn + dk) * Ln + lq] = val;
            }
        }
    }
}

// ---------------------------------------------------------------------------
// Kernel 2: flash attention, bf16 MFMA, swapped QK^T (lane-local softmax).
// 128 q-rows/block: 4 waves x 32 q-rows (MF=2 frags of 16). KV-tile 64.
// grid (Ln/128, Bn*Hn), block 256.
// ---------------------------------------------------------------------------
__global__ __launch_bounds__(256) void attn_mfma(
    const short* __restrict__ Qh, const short* __restrict__ Kh, const short* __restrict__ Vt,
    const int* __restrict__ masks, short* __restrict__ Ctx)
{
    __shared__ short Ks[64 * 64];
    __shared__ short Vs[64 * 64];
    __shared__ short Pl[4][16 * 64];   // per-wave [q][kc], swizzled, reused across mf
    __shared__ float maskAdd[64];

    const int tid  = threadIdx.x;
    const int lane = tid & 63, w = tid >> 6;
    const int l16 = lane & 15, g = lane >> 4;
    const int bh = blockIdx.y;
    const int bb = bh >> 3, h = bh & 7;
    const int q0 = blockIdx.x * 128;

    const short* Qp = Qh + (size_t)bh * Ln * DKn;
    const short* Kp = Kh + (size_t)bh * Ln * DKn;
    const short* Vp = Vt + (size_t)bh * DKn * Ln;
    const int*   mp = masks + bb * Ln;

    // Q fragments (pre-scaled by QSCALE at projection)
    bf16x8 qf[2][2];
    #pragma unroll
    for (int mf = 0; mf < 2; ++mf)
        #pragma unroll
        for (int c = 0; c < 2; ++c)
            qf[mf][c] = *(const bf16x8*)&Qp[(size_t)(q0 + w * 32 + mf * 16 + l16) * DKn + c * 32 + g * 8];

    f32x4 oacc[2][4];
    #pragma unroll
    for (int mf = 0; mf < 2; ++mf)
        #pragma unroll
        for (int d = 0; d < 4; ++d) oacc[mf][d] = (f32x4){0.f, 0.f, 0.f, 0.f};
    float m_run[2] = {-1e30f, -1e30f}, l_run[2] = {0.f, 0.f};

    for (int t = 0; t < Ln / 64; ++t) {
        const int k0 = t * 64;
        __syncthreads();
        #pragma unroll
        for (int f = 0; f < 2; ++f) {
            int lin = tid + 256 * f;
            int row = lin >> 3, c8 = lin & 7;
            bf16x8 kv = *(const bf16x8*)&Kp[(size_t)(k0 + row) * DKn + c8 * 8];
            *(bf16x8*)&Ks[row * 64 + ((c8 * 8) ^ ((row & 7) << 3))] = kv;
            bf16x8 vv = *(const bf16x8*)&Vp[(size_t)row * Ln + k0 + c8 * 8];
            *(bf16x8*)&Vs[row * 64 + ((c8 * 8) ^ ((row & 7) << 3))] = vv;
        }
        if (tid < 64) maskAdd[tid] = (mp[k0 + tid] == 0) ? -1e30f : 0.f;
        __syncthreads();

        #pragma unroll
        for (int mf = 0; mf < 2; ++mf) {
            // ---- S^T = K Q^T (swapped): lane owns q=l16, kc = kt*16 + g*4 + r
            f32x4 sv[4];
            #pragma unroll
            for (int kt = 0; kt < 4; ++kt) {
                int row = kt * 16 + l16;
                bf16x8 kf0 = *(const bf16x8*)&Ks[row * 64 + ((g * 8) ^ ((row & 7) << 3))];
                bf16x8 kf1 = *(const bf16x8*)&Ks[row * 64 + ((32 + g * 8) ^ ((row & 7) << 3))];
                f32x4 z = (f32x4){0.f, 0.f, 0.f, 0.f};
                z = __builtin_amdgcn_mfma_f32_16x16x32_bf16(kf0, qf[mf][0], z, 0, 0, 0);
                z = __builtin_amdgcn_mfma_f32_16x16x32_bf16(kf1, qf[mf][1], z, 0, 0, 0);
                sv[kt] = z;
            }
            // mask add (scores already in log2 domain via QSCALE)
            #pragma unroll
            for (int kt = 0; kt < 4; ++kt) {
                f32x4 mk = *(const f32x4*)&maskAdd[kt * 16 + g * 4];
                sv[kt] += mk;
            }
            // ---- lane-local row max
            float mt = sv[0][0];
            #pragma unroll
            for (int kt = 0; kt < 4; ++kt)
                #pragma unroll
                for (int r = 0; r < 4; ++r) mt = fmaxf(mt, sv[kt][r]);
            mt = fmaxf(mt, __shfl_xor(mt, 16));
            mt = fmaxf(mt, __shfl_xor(mt, 32));
            float mnew = fmaxf(m_run[mf], mt);
            float fac  = exp2f(m_run[mf] - mnew);
            m_run[mf]  = mnew;
            float rs = 0.f;
            #pragma unroll
            for (int kt = 0; kt < 4; ++kt)
                #pragma unroll
                for (int r = 0; r < 4; ++r) {
                    float pv = exp2f(sv[kt][r] - mnew);
                    sv[kt][r] = pv; rs += pv;
                }
            rs += __shfl_xor(rs, 16);
            rs += __shfl_xor(rs, 32);
            l_run[mf] = l_run[mf] * fac + rs;

            // ---- rescale O rows (row q=g*4+r needs fac computed by lane l16=g*4+r)
            #pragma unroll
            for (int r = 0; r < 4; ++r) {
                float facr = __shfl(fac, g * 20 + r);
                #pragma unroll
                for (int d = 0; d < 4; ++d) oacc[mf][d][r] *= facr;
            }

            // ---- P -> wave-private LDS as packed bf16 pairs (u32 writes)
            #pragma unroll
            for (int kt = 0; kt < 4; ++kt)
                #pragma unroll
                for (int j = 0; j < 2; ++j) {
                    unsigned pv = pkbf(sv[kt][2 * j], sv[kt][2 * j + 1]);
                    int col = kt * 16 + g * 4 + 2 * j;
                    *(unsigned*)&Pl[w][l16 * 64 + (col ^ ((l16 & 7) << 3))] = pv;
                }

            // ---- O += P V
            #pragma unroll
            for (int c = 0; c < 2; ++c) {
                bf16x8 pf = *(const bf16x8*)&Pl[w][l16 * 64 + ((c * 32 + g * 8) ^ ((l16 & 7) << 3))];
                #pragma unroll
                for (int d = 0; d < 4; ++d) {
                    int vrow = d * 16 + l16;
                    bf16x8 vf = *(const bf16x8*)&Vs[vrow * 64 + ((c * 32 + g * 8) ^ ((vrow & 7) << 3))];
                    oacc[mf][d] = __builtin_amdgcn_mfma_f32_16x16x32_bf16(pf, vf, oacc[mf][d], 0, 0, 0);
                }
            }
        }
    }

    // epilogue: normalize, write Ctx bf16 [b*Ln+l][h*64+dk]
    #pragma unroll
    for (int mf = 0; mf < 2; ++mf)
        #pragma unroll
        for (int r = 0; r < 4; ++r) {
            float lr  = __shfl(l_run[mf], g * 20 + r);
            float inv = 1.0f / lr;
            size_t mrow = (size_t)bb * Ln + q0 + w * 32 + mf * 16 + g * 4 + r;
            #pragma unroll
            for (int d = 0; d < 4; ++d)
                Ctx[mrow * Dn + h * 64 + d * 16 + l16] = f2bf(oacc[mf][d][r] * inv);
        }
}

// ---------------------------------------------------------------------------
// Kernel 3: output projection, bf16 MFMA. grid (Mtot/128, Dn/128), block 256.
// ---------------------------------------------------------------------------
__global__ __launch_bounds__(256) void out_proj_mfma(
    const short* __restrict__ Ctx, const float* __restrict__ W,
    const float* __restrict__ bias, float* __restrict__ Out)
{
    __shared__ short As[128 * 72];
    __shared__ short Bs[128 * 72];

    const int tid  = threadIdx.x;
    const int lane = tid & 63, w = tid >> 6;
    const int wr = w >> 1, wc = w & 1;
    const int l16 = lane & 15, g = lane >> 4;
    const int m0 = blockIdx.x * 128, n0 = blockIdx.y * 128;

    f32x4 acc[4][4];
    #pragma unroll
    for (int i = 0; i < 4; ++i)
        #pragma unroll
        for (int j = 0; j < 4; ++j)
            acc[i][j] = (f32x4){0.f, 0.f, 0.f, 0.f};

    for (int k0 = 0; k0 < Dn; k0 += 64) {
        #pragma unroll
        for (int f = 0; f < 4; ++f) {
            int lin = tid + 256 * f;
            int row = lin >> 3, c8 = lin & 7;
            bf16x8 av = *(const bf16x8*)&Ctx[(size_t)(m0 + row) * Dn + k0 + c8 * 8];
            *(bf16x8*)&As[row * 72 + c8 * 8] = av;
        }
        #pragma unroll
        for (int f = 0; f < 8; ++f) {
            int lin = tid + 256 * f;
            int row = lin >> 4, c4 = lin & 15;
            float4 wv4 = *(const float4*)&W[(size_t)(n0 + row) * Dn + k0 + c4 * 4];
            bf16x4 wb; wb[0] = f2bf(wv4.x); wb[1] = f2bf(wv4.y); wb[2] = f2bf(wv4.z); wb[3] = f2bf(wv4.w);
            *(bf16x4*)&Bs[row * 72 + c4 * 4] = wb;
        }
        __syncthreads();

        bf16x8 af[4][2], bfv[4][2];
        #pragma unroll
        for (int i = 0; i < 4; ++i)
            #pragma unroll
            for (int c = 0; c < 2; ++c)
                af[i][c] = *(const bf16x8*)&As[(wr * 64 + i * 16 + l16) * 72 + c * 32 + g * 8];
        #pragma unroll
        for (int j = 0; j < 4; ++j)
            #pragma unroll
            for (int c = 0; c < 2; ++c)
                bfv[j][c] = *(const bf16x8*)&Bs[(wc * 64 + j * 16 + l16) * 72 + c * 32 + g * 8];

        #pragma unroll
        for (int i = 0; i < 4; ++i)
            #pragma unroll
            for (int j = 0; j < 4; ++j) {
                acc[i][j] = __builtin_amdgcn_mfma_f32_16x16x32_bf16(af[i][0], bfv[j][0], acc[i][j], 0, 0, 0);
                acc[i][j] = __builtin_amdgcn_mfma_f32_16x16x32_bf16(af[i][1], bfv[j][1], acc[i][j], 0, 0, 0);
            }
        __syncthreads();
    }

    #pragma unroll
    for (int i = 0; i < 4; ++i) {
        #pragma unroll
        for (int j = 0; j < 4; ++j) {
            int n = n0 + wc * 64 + j * 16 + l16;
            float bval = bias[n];
            #pragma unroll
            for (int r = 0; r < 4; ++r) {
                int m = m0 + wr * 64 + i * 16 + g * 4 + r;
                Out[(size_t)m * Dn + n] = acc[i][j][r] + bval;
            }
        }
    }
}

// ---------------------------------------------------------------------------
extern "C" void kernel_launch(void* const* d_in, const int* in_sizes, int n_in,
                              void* d_out, int out_size, void* d_ws, size_t ws_size,
                              hipStream_t stream)
{
    (void)in_sizes; (void)n_in; (void)out_size; (void)ws_size;
    const float* q    = (const float*)d_in[0];
    const float* k    = (const float*)d_in[1];
    const float* v    = (const float*)d_in[2];
    const int*   mks  = (const int*)  d_in[3];
    const float* wq_w = (const float*)d_in[4];
    const float* wq_b = (const float*)d_in[5];
    const float* wk_w = (const float*)d_in[6];
    const float* wk_b = (const float*)d_in[7];
    const float* wv_w = (const float*)d_in[8];
    const float* wv_b = (const float*)d_in[9];
    const float* wo_w = (const float*)d_in[10];
    const float* wo_b = (const float*)d_in[11];
    float* out = (float*)d_out;

    const size_t headElems = (size_t)Bn * Hn * Ln * DKn;
    short* ws  = (short*)d_ws;
    short* Qh  = ws;
    short* Kh  = ws + headElems;
    short* Vt  = ws + 2 * headElems;
    short* Ctx = ws + 3 * headElems;

    qkv_proj_mfma<<<dim3(Mtot / 128, Dn / 128, 3), 256, 0, stream>>>(
        q, k, v, wq_w, wk_w, wv_w, wq_b, wk_b, wv_b, Qh, Kh, Vt);

    attn_mfma<<<dim3(Ln / 128, Bn * Hn), 256, 0, stream>>>(Qh, Kh, Vt, mks, Ctx);

    out_proj_mfma<<<dim3(Mtot / 128, Dn / 128), 256, 0, stream>>>(Ctx, wo_w, wo_b, out);
}

// Round 4
// 149.159 us; speedup vs baseline: 5.8173x; 1.1173x over previous
//
#include <hip/hip_runtime.h>
#include <hip/hip_bf16.h>
#include <cstddef>

typedef __attribute__((ext_vector_type(8))) short bf16x8;
typedef __attribute__((ext_vector_type(4))) short bf16x4;
typedef __attribute__((ext_vector_type(4))) float f32x4;

constexpr int Bn = 4, Ln = 2048, Dn = 512, Hn = 8, DKn = 64, Mtot = 8192;
// 1/sqrt(DK) * log2(e): softmax computed in exp2 domain
constexpr float QSCALE = 0.125f * 1.44269504088896341f;

__device__ inline short f2bf(float x) {
    __hip_bfloat16 h = __float2bfloat16(x);   // RNE, hardware cvt
    short s; __builtin_memcpy(&s, &h, 2); return s;
}
__device__ inline unsigned pkbf(float lo, float hi) {
    unsigned a = (unsigned short)f2bf(lo);
    unsigned b = (unsigned short)f2bf(hi);
    return a | (b << 16);
}

// ---------------------------------------------------------------------------
// Kernel 0: mask -> additive f32 (-1e30 / 0), read by attn as f32x4 from L2.
// ---------------------------------------------------------------------------
__global__ __launch_bounds__(256) void mask_prep(
    const int* __restrict__ masks, float* __restrict__ maskF)
{
    int i = blockIdx.x * 256 + threadIdx.x;
    if (i < Bn * Ln) maskF[i] = (masks[i] == 0) ? -1e30f : 0.f;
}

// ---------------------------------------------------------------------------
// Kernel 1: QKV projection, bf16 MFMA.  C = X @ W^T + b.
// Q output pre-scaled by QSCALE.  Q,K: bf16 [b][h][l][dk]; V: bf16 [b][h][dk][l].
// Tile 128x128, BK=64, 4 waves (2x2). grid (Mtot/128, Dn/128, 3), block 256.
// ---------------------------------------------------------------------------
__global__ __launch_bounds__(256) void qkv_proj_mfma(
    const float* __restrict__ q, const float* __restrict__ k, const float* __restrict__ v,
    const float* __restrict__ wq, const float* __restrict__ wk, const float* __restrict__ wv,
    const float* __restrict__ bq, const float* __restrict__ bk, const float* __restrict__ bv,
    short* __restrict__ Qh, short* __restrict__ Kh, short* __restrict__ Vt)
{
    const int p = blockIdx.z;
    const float* X    = (p == 0) ? q  : (p == 1) ? k  : v;
    const float* W    = (p == 0) ? wq : (p == 1) ? wk : wv;
    const float* bias = (p == 0) ? bq : (p == 1) ? bk : bv;
    short*       O    = (p == 0) ? Qh : (p == 1) ? Kh : Vt;
    const float scl   = (p == 0) ? QSCALE : 1.0f;

    __shared__ short As[128 * 72];
    __shared__ short Bs[128 * 72];

    const int tid  = threadIdx.x;
    const int lane = tid & 63, w = tid >> 6;
    const int wr = w >> 1, wc = w & 1;
    const int l16 = lane & 15, g = lane >> 4;
    const int m0 = blockIdx.x * 128, n0 = blockIdx.y * 128;

    f32x4 acc[4][4];
    #pragma unroll
    for (int i = 0; i < 4; ++i)
        #pragma unroll
        for (int j = 0; j < 4; ++j)
            acc[i][j] = (f32x4){0.f, 0.f, 0.f, 0.f};

    for (int k0 = 0; k0 < Dn; k0 += 64) {
        #pragma unroll
        for (int f = 0; f < 8; ++f) {
            int lin = tid + 256 * f;
            int row = lin >> 4, c4 = lin & 15;
            float4 xv = *(const float4*)&X[(size_t)(m0 + row) * Dn + k0 + c4 * 4];
            bf16x4 xb; xb[0] = f2bf(xv.x); xb[1] = f2bf(xv.y); xb[2] = f2bf(xv.z); xb[3] = f2bf(xv.w);
            *(bf16x4*)&As[row * 72 + c4 * 4] = xb;
            float4 wv4 = *(const float4*)&W[(size_t)(n0 + row) * Dn + k0 + c4 * 4];
            bf16x4 wb; wb[0] = f2bf(wv4.x); wb[1] = f2bf(wv4.y); wb[2] = f2bf(wv4.z); wb[3] = f2bf(wv4.w);
            *(bf16x4*)&Bs[row * 72 + c4 * 4] = wb;
        }
        __syncthreads();

        bf16x8 af[4][2], bfv[4][2];
        #pragma unroll
        for (int i = 0; i < 4; ++i)
            #pragma unroll
            for (int c = 0; c < 2; ++c)
                af[i][c] = *(const bf16x8*)&As[(wr * 64 + i * 16 + l16) * 72 + c * 32 + g * 8];
        #pragma unroll
        for (int j = 0; j < 4; ++j)
            #pragma unroll
            for (int c = 0; c < 2; ++c)
                bfv[j][c] = *(const bf16x8*)&Bs[(wc * 64 + j * 16 + l16) * 72 + c * 32 + g * 8];

        #pragma unroll
        for (int i = 0; i < 4; ++i)
            #pragma unroll
            for (int j = 0; j < 4; ++j) {
                acc[i][j] = __builtin_amdgcn_mfma_f32_16x16x32_bf16(af[i][0], bfv[j][0], acc[i][j], 0, 0, 0);
                acc[i][j] = __builtin_amdgcn_mfma_f32_16x16x32_bf16(af[i][1], bfv[j][1], acc[i][j], 0, 0, 0);
            }
        __syncthreads();
    }

    const int bb = m0 >> 11;
    #pragma unroll
    for (int i = 0; i < 4; ++i) {
        #pragma unroll
        for (int j = 0; j < 4; ++j) {
            int n  = n0 + wc * 64 + j * 16 + l16;
            int h  = n >> 6, dk = n & 63;
            float bval = bias[n];
            #pragma unroll
            for (int r = 0; r < 4; ++r) {
                int m  = m0 + wr * 64 + i * 16 + g * 4 + r;
                int lq = m & (Ln - 1);
                short val = f2bf((acc[i][j][r] + bval) * scl);
                if (p < 2)
                    O[(((size_t)bb * Hn + h) * Ln + lq) * DKn + dk] = val;
                else
                    O[(((size_t)bb * Hn + h) * DKn + dk) * Ln + lq] = val;
            }
        }
    }
}

// ---------------------------------------------------------------------------
// Kernel 2: flash attention, bf16 MFMA, swapped QK^T, double-buffered K/V,
// depth-2 register prefetch, ONE barrier per KV tile.
// 64 q/block (4 waves x 16), KV-tile 64. grid (Ln/64, Bn*Hn), block 256.
// ---------------------------------------------------------------------------
__global__ __launch_bounds__(256) void attn_mfma(
    const short* __restrict__ Qh, const short* __restrict__ Kh, const short* __restrict__ Vt,
    const float* __restrict__ maskF, short* __restrict__ Ctx)
{
    __shared__ short Ks[2][64 * 64];
    __shared__ short Vs[2][64 * 64];
    __shared__ short Pl[4][16 * 64];

    const int tid  = threadIdx.x;
    const int lane = tid & 63, w = tid >> 6;
    const int l16 = lane & 15, g = lane >> 4;
    const int bh = blockIdx.y;
    const int bb = bh >> 3, h = bh & 7;
    const int q0 = blockIdx.x * 64;

    const short* Qp = Qh + (size_t)bh * Ln * DKn;
    const short* Kp = Kh + (size_t)bh * Ln * DKn;
    const short* Vp = Vt + (size_t)bh * DKn * Ln;
    const float* mp = maskF + bb * Ln;

    // Q fragments (pre-scaled by QSCALE at projection)
    bf16x8 qf0 = *(const bf16x8*)&Qp[(size_t)(q0 + w * 16 + l16) * DKn + g * 8];
    bf16x8 qf1 = *(const bf16x8*)&Qp[(size_t)(q0 + w * 16 + l16) * DKn + 32 + g * 8];

    // ---- loop-invariant staging addresses (thread stages 2 chunks of K and V)
    const int srow0 = tid >> 3, sc8 = tid & 7, srow1 = srow0 + 32;
    const int wO0 = srow0 * 64 + ((sc8 * 8) ^ ((srow0 & 7) << 3));
    const int wO1 = srow1 * 64 + ((sc8 * 8) ^ ((srow1 & 7) << 3));
    const short* Kg0 = Kp + (size_t)srow0 * DKn + sc8 * 8;   // + t*64*DKn per tile
    const short* Kg1 = Kp + (size_t)srow1 * DKn + sc8 * 8;
    const short* Vg0 = Vp + (size_t)srow0 * Ln + sc8 * 8;    // + t*64 per tile
    const short* Vg1 = Vp + (size_t)srow1 * Ln + sc8 * 8;

    // ---- loop-invariant fragment read offsets (K and V share the formula)
    int kofs[4][2];
    #pragma unroll
    for (int kt = 0; kt < 4; ++kt) {
        int row = kt * 16 + l16;
        kofs[kt][0] = row * 64 + ((g * 8) ^ ((row & 7) << 3));
        kofs[kt][1] = row * 64 + ((32 + g * 8) ^ ((row & 7) << 3));
    }
    int pwb[4];   // P write base per kt (2j added later; safe: XOR bits >= 3)
    #pragma unroll
    for (int kt = 0; kt < 4; ++kt)
        pwb[kt] = l16 * 64 + ((kt * 16 + g * 4) ^ ((l16 & 7) << 3));
    int prd[2];
    #pragma unroll
    for (int c = 0; c < 2; ++c)
        prd[c] = l16 * 64 + ((c * 32 + g * 8) ^ ((l16 & 7) << 3));

    f32x4 oacc[4];
    #pragma unroll
    for (int d = 0; d < 4; ++d) oacc[d] = (f32x4){0.f, 0.f, 0.f, 0.f};
    float m_run = -1e30f, l_run = 0.f;

    // ---- prologue: stage tile 0, prefetch tile 1
    bf16x8 kr0 = *(const bf16x8*)&Kg0[0];
    bf16x8 kr1 = *(const bf16x8*)&Kg1[0];
    bf16x8 vr0 = *(const bf16x8*)&Vg0[0];
    bf16x8 vr1 = *(const bf16x8*)&Vg1[0];
    *(bf16x8*)&Ks[0][wO0] = kr0;  *(bf16x8*)&Ks[0][wO1] = kr1;
    *(bf16x8*)&Vs[0][wO0] = vr0;  *(bf16x8*)&Vs[0][wO1] = vr1;
    kr0 = *(const bf16x8*)&Kg0[(size_t)64 * DKn];
    kr1 = *(const bf16x8*)&Kg1[(size_t)64 * DKn];
    vr0 = *(const bf16x8*)&Vg0[64];
    vr1 = *(const bf16x8*)&Vg1[64];
    __syncthreads();

    int c = 0;
    for (int t = 0; t < Ln / 64; ++t) {
        // ---- write next tile into the other buffer; prefetch t+2
        if (t < Ln / 64 - 1) {
            *(bf16x8*)&Ks[c ^ 1][wO0] = kr0;  *(bf16x8*)&Ks[c ^ 1][wO1] = kr1;
            *(bf16x8*)&Vs[c ^ 1][wO0] = vr0;  *(bf16x8*)&Vs[c ^ 1][wO1] = vr1;
            int tn = (t + 2 < Ln / 64) ? t + 2 : Ln / 64 - 1;
            kr0 = *(const bf16x8*)&Kg0[(size_t)tn * 64 * DKn];
            kr1 = *(const bf16x8*)&Kg1[(size_t)tn * 64 * DKn];
            vr0 = *(const bf16x8*)&Vg0[(size_t)tn * 64];
            vr1 = *(const bf16x8*)&Vg1[(size_t)tn * 64];
        }

        // ---- mask (f32 additive, from L2)
        f32x4 mk[4];
        #pragma unroll
        for (int kt = 0; kt < 4; ++kt)
            mk[kt] = *(const f32x4*)&mp[t * 64 + kt * 16 + g * 4];

        // ---- S^T = K Q^T (swapped): lane owns q=l16, kc = kt*16 + g*4 + r
        f32x4 sv[4];
        __builtin_amdgcn_s_setprio(1);
        #pragma unroll
        for (int kt = 0; kt < 4; ++kt) {
            bf16x8 kf0 = *(const bf16x8*)&Ks[c][kofs[kt][0]];
            bf16x8 kf1 = *(const bf16x8*)&Ks[c][kofs[kt][1]];
            f32x4 z = (f32x4){0.f, 0.f, 0.f, 0.f};
            z = __builtin_amdgcn_mfma_f32_16x16x32_bf16(kf0, qf0, z, 0, 0, 0);
            z = __builtin_amdgcn_mfma_f32_16x16x32_bf16(kf1, qf1, z, 0, 0, 0);
            sv[kt] = z;
        }
        __builtin_amdgcn_s_setprio(0);
        #pragma unroll
        for (int kt = 0; kt < 4; ++kt) sv[kt] += mk[kt];

        // ---- online softmax (lane-local row, scores already in log2 domain)
        float mt = sv[0][0];
        #pragma unroll
        for (int kt = 0; kt < 4; ++kt)
            #pragma unroll
            for (int r = 0; r < 4; ++r) mt = fmaxf(mt, sv[kt][r]);
        mt = fmaxf(mt, __shfl_xor(mt, 16));
        mt = fmaxf(mt, __shfl_xor(mt, 32));
        float mnew = fmaxf(m_run, mt);
        float fac  = exp2f(m_run - mnew);
        m_run = mnew;
        float rs = 0.f;
        #pragma unroll
        for (int kt = 0; kt < 4; ++kt)
            #pragma unroll
            for (int r = 0; r < 4; ++r) {
                float pv = exp2f(sv[kt][r] - mnew);
                sv[kt][r] = pv; rs += pv;
            }
        rs += __shfl_xor(rs, 16);
        rs += __shfl_xor(rs, 32);
        l_run = l_run * fac + rs;

        // ---- rescale O rows (row q=g*4+r gets fac from lane l16=g*4+r)
        #pragma unroll
        for (int r = 0; r < 4; ++r) {
            float facr = __shfl(fac, g * 20 + r);
            #pragma unroll
            for (int d = 0; d < 4; ++d) oacc[d][r] *= facr;
        }

        // ---- P -> wave-private LDS as packed bf16 pairs
        #pragma unroll
        for (int kt = 0; kt < 4; ++kt)
            #pragma unroll
            for (int j = 0; j < 2; ++j)
                *(unsigned*)&Pl[w][pwb[kt] + 2 * j] = pkbf(sv[kt][2 * j], sv[kt][2 * j + 1]);

        // ---- O += P V
        __builtin_amdgcn_s_setprio(1);
        #pragma unroll
        for (int cc = 0; cc < 2; ++cc) {
            bf16x8 pf = *(const bf16x8*)&Pl[w][prd[cc]];
            #pragma unroll
            for (int d = 0; d < 4; ++d) {
                bf16x8 vf = *(const bf16x8*)&Vs[c][kofs[d][cc]];
                oacc[d] = __builtin_amdgcn_mfma_f32_16x16x32_bf16(pf, vf, oacc[d], 0, 0, 0);
            }
        }
        __builtin_amdgcn_s_setprio(0);

        __syncthreads();
        c ^= 1;
    }

    // epilogue: normalize, write Ctx bf16 [b*Ln+l][h*64+dk]
    #pragma unroll
    for (int r = 0; r < 4; ++r) {
        float lr  = __shfl(l_run, g * 20 + r);
        float inv = 1.0f / lr;
        size_t mrow = (size_t)bb * Ln + q0 + w * 16 + g * 4 + r;
        #pragma unroll
        for (int d = 0; d < 4; ++d)
            Ctx[mrow * Dn + h * 64 + d * 16 + l16] = f2bf(oacc[d][r] * inv);
    }
}

// ---------------------------------------------------------------------------
// Kernel 3: output projection, bf16 MFMA. grid (Mtot/128, Dn/128), block 256.
// ---------------------------------------------------------------------------
__global__ __launch_bounds__(256) void out_proj_mfma(
    const short* __restrict__ Ctx, const float* __restrict__ W,
    const float* __restrict__ bias, float* __restrict__ Out)
{
    __shared__ short As[128 * 72];
    __shared__ short Bs[128 * 72];

    const int tid  = threadIdx.x;
    const int lane = tid & 63, w = tid >> 6;
    const int wr = w >> 1, wc = w & 1;
    const int l16 = lane & 15, g = lane >> 4;
    const int m0 = blockIdx.x * 128, n0 = blockIdx.y * 128;

    f32x4 acc[4][4];
    #pragma unroll
    for (int i = 0; i < 4; ++i)
        #pragma unroll
        for (int j = 0; j < 4; ++j)
            acc[i][j] = (f32x4){0.f, 0.f, 0.f, 0.f};

    for (int k0 = 0; k0 < Dn; k0 += 64) {
        #pragma unroll
        for (int f = 0; f < 4; ++f) {
            int lin = tid + 256 * f;
            int row = lin >> 3, c8 = lin & 7;
            bf16x8 av = *(const bf16x8*)&Ctx[(size_t)(m0 + row) * Dn + k0 + c8 * 8];
            *(bf16x8*)&As[row * 72 + c8 * 8] = av;
        }
        #pragma unroll
        for (int f = 0; f < 8; ++f) {
            int lin = tid + 256 * f;
            int row = lin >> 4, c4 = lin & 15;
            float4 wv4 = *(const float4*)&W[(size_t)(n0 + row) * Dn + k0 + c4 * 4];
            bf16x4 wb; wb[0] = f2bf(wv4.x); wb[1] = f2bf(wv4.y); wb[2] = f2bf(wv4.z); wb[3] = f2bf(wv4.w);
            *(bf16x4*)&Bs[row * 72 + c4 * 4] = wb;
        }
        __syncthreads();

        bf16x8 af[4][2], bfv[4][2];
        #pragma unroll
        for (int i = 0; i < 4; ++i)
            #pragma unroll
            for (int c = 0; c < 2; ++c)
                af[i][c] = *(const bf16x8*)&As[(wr * 64 + i * 16 + l16) * 72 + c * 32 + g * 8];
        #pragma unroll
        for (int j = 0; j < 4; ++j)
            #pragma unroll
            for (int c = 0; c < 2; ++c)
                bfv[j][c] = *(const bf16x8*)&Bs[(wc * 64 + j * 16 + l16) * 72 + c * 32 + g * 8];

        #pragma unroll
        for (int i = 0; i < 4; ++i)
            #pragma unroll
            for (int j = 0; j < 4; ++j) {
                acc[i][j] = __builtin_amdgcn_mfma_f32_16x16x32_bf16(af[i][0], bfv[j][0], acc[i][j], 0, 0, 0);
                acc[i][j] = __builtin_amdgcn_mfma_f32_16x16x32_bf16(af[i][1], bfv[j][1], acc[i][j], 0, 0, 0);
            }
        __syncthreads();
    }

    #pragma unroll
    for (int i = 0; i < 4; ++i) {
        #pragma unroll
        for (int j = 0; j < 4; ++j) {
            int n = n0 + wc * 64 + j * 16 + l16;
            float bval = bias[n];
            #pragma unroll
            for (int r = 0; r < 4; ++r) {
                int m = m0 + wr * 64 + i * 16 + g * 4 + r;
                Out[(size_t)m * Dn + n] = acc[i][j][r] + bval;
            }
        }
    }
}

// ---------------------------------------------------------------------------
extern "C" void kernel_launch(void* const* d_in, const int* in_sizes, int n_in,
                              void* d_out, int out_size, void* d_ws, size_t ws_size,
                              hipStream_t stream)
{
    (void)in_sizes; (void)n_in; (void)out_size; (void)ws_size;
    const float* q    = (const float*)d_in[0];
    const float* k    = (const float*)d_in[1];
    const float* v    = (const float*)d_in[2];
    const int*   mks  = (const int*)  d_in[3];
    const float* wq_w = (const float*)d_in[4];
    const float* wq_b = (const float*)d_in[5];
    const float* wk_w = (const float*)d_in[6];
    const float* wk_b = (const float*)d_in[7];
    const float* wv_w = (const float*)d_in[8];
    const float* wv_b = (const float*)d_in[9];
    const float* wo_w = (const float*)d_in[10];
    const float* wo_b = (const float*)d_in[11];
    float* out = (float*)d_out;

    const size_t headElems = (size_t)Bn * Hn * Ln * DKn;
    short* ws  = (short*)d_ws;
    short* Qh  = ws;
    short* Kh  = ws + headElems;
    short* Vt  = ws + 2 * headElems;
    short* Ctx = ws + 3 * headElems;
    float* maskF = (float*)(ws + 4 * headElems);

    mask_prep<<<dim3((Bn * Ln + 255) / 256), 256, 0, stream>>>(mks, maskF);

    qkv_proj_mfma<<<dim3(Mtot / 128, Dn / 128, 3), 256, 0, stream>>>(
        q, k, v, wq_w, wk_w, wv_w, wq_b, wk_b, wv_b, Qh, Kh, Vt);

    attn_mfma<<<dim3(Ln / 64, Bn * Hn), 256, 0, stream>>>(Qh, Kh, Vt, maskF, Ctx);

    out_proj_mfma<<<dim3(Mtot / 128, Dn / 128), 256, 0, stream>>>(Ctx, wo_w, wo_b, out);
}

// Round 5
// 145.356 us; speedup vs baseline: 5.9695x; 1.0262x over previous
//
#include <hip/hip_runtime.h>
#include <hip/hip_bf16.h>
#include <cstddef>

typedef __attribute__((ext_vector_type(8))) short bf16x8;
typedef __attribute__((ext_vector_type(4))) short bf16x4;
typedef __attribute__((ext_vector_type(4))) float f32x4;

constexpr int Bn = 4, Ln = 2048, Dn = 512, Hn = 8, DKn = 64, Mtot = 8192;
// 1/sqrt(DK) * log2(e): softmax computed in exp2 domain
constexpr float QSCALE = 0.125f * 1.44269504088896341f;

// hardware packed fp32->bf16 (RNE), 2 values per instruction
__device__ inline unsigned cvt_pk_bf16(float lo, float hi) {
    unsigned r;
    asm("v_cvt_pk_bf16_f32 %0, %1, %2" : "=v"(r) : "v"(lo), "v"(hi));
    return r;
}
// scalar fp32->bf16 RNE (finite inputs only)
__device__ inline short f2bf(float x) {
    union { float f; unsigned u; } v; v.f = x;
    unsigned r = v.u + 0x7fffu + ((v.u >> 16) & 1u);
    return (short)(r >> 16);
}

// ---------------------------------------------------------------------------
// Kernel 0: mask -> additive f32 (-1e30 / 0)
// ---------------------------------------------------------------------------
__global__ __launch_bounds__(256) void mask_prep(
    const int* __restrict__ masks, float* __restrict__ maskF)
{
    int i = blockIdx.x * 256 + threadIdx.x;
    if (i < Bn * Ln) maskF[i] = (masks[i] == 0) ? -1e30f : 0.f;
}

// ---------------------------------------------------------------------------
// Kernel 1: QKV projection, bf16 MFMA.  C = X @ W^T + b.
// Q pre-scaled by QSCALE.  Q,K: bf16 [b][h][l][dk]; V: bf16 [b][h][dk][l].
// ---------------------------------------------------------------------------
__global__ __launch_bounds__(256) void qkv_proj_mfma(
    const float* __restrict__ q, const float* __restrict__ k, const float* __restrict__ v,
    const float* __restrict__ wq, const float* __restrict__ wk, const float* __restrict__ wv,
    const float* __restrict__ bq, const float* __restrict__ bk, const float* __restrict__ bv,
    short* __restrict__ Qh, short* __restrict__ Kh, short* __restrict__ Vt)
{
    const int p = blockIdx.z;
    const float* X    = (p == 0) ? q  : (p == 1) ? k  : v;
    const float* W    = (p == 0) ? wq : (p == 1) ? wk : wv;
    const float* bias = (p == 0) ? bq : (p == 1) ? bk : bv;
    short*       O    = (p == 0) ? Qh : (p == 1) ? Kh : Vt;
    const float scl   = (p == 0) ? QSCALE : 1.0f;

    __shared__ short As[128 * 72];
    __shared__ short Bs[128 * 72];

    const int tid  = threadIdx.x;
    const int lane = tid & 63, w = tid >> 6;
    const int wr = w >> 1, wc = w & 1;
    const int l16 = lane & 15, g = lane >> 4;
    const int m0 = blockIdx.x * 128, n0 = blockIdx.y * 128;

    f32x4 acc[4][4];
    #pragma unroll
    for (int i = 0; i < 4; ++i)
        #pragma unroll
        for (int j = 0; j < 4; ++j)
            acc[i][j] = (f32x4){0.f, 0.f, 0.f, 0.f};

    for (int k0 = 0; k0 < Dn; k0 += 64) {
        #pragma unroll
        for (int f = 0; f < 8; ++f) {
            int lin = tid + 256 * f;
            int row = lin >> 4, c4 = lin & 15;
            float4 xv = *(const float4*)&X[(size_t)(m0 + row) * Dn + k0 + c4 * 4];
            uint2 xp = {cvt_pk_bf16(xv.x, xv.y), cvt_pk_bf16(xv.z, xv.w)};
            *(uint2*)&As[row * 72 + c4 * 4] = xp;
            float4 wv4 = *(const float4*)&W[(size_t)(n0 + row) * Dn + k0 + c4 * 4];
            uint2 wp = {cvt_pk_bf16(wv4.x, wv4.y), cvt_pk_bf16(wv4.z, wv4.w)};
            *(uint2*)&Bs[row * 72 + c4 * 4] = wp;
        }
        __syncthreads();

        bf16x8 af[4][2], bfv[4][2];
        #pragma unroll
        for (int i = 0; i < 4; ++i)
            #pragma unroll
            for (int c = 0; c < 2; ++c)
                af[i][c] = *(const bf16x8*)&As[(wr * 64 + i * 16 + l16) * 72 + c * 32 + g * 8];
        #pragma unroll
        for (int j = 0; j < 4; ++j)
            #pragma unroll
            for (int c = 0; c < 2; ++c)
                bfv[j][c] = *(const bf16x8*)&Bs[(wc * 64 + j * 16 + l16) * 72 + c * 32 + g * 8];

        #pragma unroll
        for (int i = 0; i < 4; ++i)
            #pragma unroll
            for (int j = 0; j < 4; ++j) {
                acc[i][j] = __builtin_amdgcn_mfma_f32_16x16x32_bf16(af[i][0], bfv[j][0], acc[i][j], 0, 0, 0);
                acc[i][j] = __builtin_amdgcn_mfma_f32_16x16x32_bf16(af[i][1], bfv[j][1], acc[i][j], 0, 0, 0);
            }
        __syncthreads();
    }

    const int bb = m0 >> 11;
    #pragma unroll
    for (int i = 0; i < 4; ++i) {
        #pragma unroll
        for (int j = 0; j < 4; ++j) {
            int n  = n0 + wc * 64 + j * 16 + l16;
            int h  = n >> 6, dk = n & 63;
            float bval = bias[n];
            #pragma unroll
            for (int r = 0; r < 4; ++r) {
                int m  = m0 + wr * 64 + i * 16 + g * 4 + r;
                int lq = m & (Ln - 1);
                short val = f2bf((acc[i][j][r] + bval) * scl);
                if (p < 2)
                    O[(((size_t)bb * Hn + h) * Ln + lq) * DKn + dk] = val;
                else
                    O[(((size_t)bb * Hn + h) * DKn + dk) * Ln + lq] = val;
            }
        }
    }
}

// ---------------------------------------------------------------------------
// Kernel 2: flash attention, bf16 MFMA, swapped QK^T, O^T orientation,
// defer-max (THR=8 log2), MFMA-accumulated row sums, dbuf K/V staging.
// 64 q/block (4 waves x 16), KV-tile 64. grid (Ln/64, Bn*Hn), block 256.
// ---------------------------------------------------------------------------
__global__ __launch_bounds__(256) void attn_mfma(
    const short* __restrict__ Qh, const short* __restrict__ Kh, const short* __restrict__ Vt,
    const float* __restrict__ maskF, short* __restrict__ Ctx)
{
    __shared__ short Ks[2][64 * 64];
    __shared__ short Vs[2][64 * 64];
    __shared__ short Pl[4][16 * 64];

    const int tid  = threadIdx.x;
    const int lane = tid & 63, w = tid >> 6;
    const int l16 = lane & 15, g = lane >> 4;
    const int bh = blockIdx.y;
    const int bb = bh >> 3, h = bh & 7;
    const int q0 = blockIdx.x * 64;
    const int NT = Ln / 64;

    const short* Qp = Qh + (size_t)bh * Ln * DKn;
    const short* Kp = Kh + (size_t)bh * Ln * DKn;
    const short* Vp = Vt + (size_t)bh * DKn * Ln;
    const float* mp = maskF + bb * Ln;

    bf16x8 qf0 = *(const bf16x8*)&Qp[(size_t)(q0 + w * 16 + l16) * DKn + g * 8];
    bf16x8 qf1 = *(const bf16x8*)&Qp[(size_t)(q0 + w * 16 + l16) * DKn + 32 + g * 8];

    // all-ones bf16 A-fragment for MFMA row sums
    constexpr short BF1 = (short)0x3F80;
    const bf16x8 ones = {BF1, BF1, BF1, BF1, BF1, BF1, BF1, BF1};

    // staging addresses (thread stages 2 chunks of K and V per tile)
    const int srow0 = tid >> 3, sc8 = tid & 7, srow1 = srow0 + 32;
    const int wO0 = srow0 * 64 + ((sc8 * 8) ^ ((srow0 & 7) << 3));
    const int wO1 = srow1 * 64 + ((sc8 * 8) ^ ((srow1 & 7) << 3));
    const short* Kg0 = Kp + srow0 * DKn + sc8 * 8;
    const short* Kg1 = Kp + srow1 * DKn + sc8 * 8;
    const short* Vg0 = Vp + srow0 * Ln + sc8 * 8;
    const short* Vg1 = Vp + srow1 * Ln + sc8 * 8;

    // fragment read offsets (K-frag and V-frag share the formula)
    int kofs[4][2];
    #pragma unroll
    for (int kt = 0; kt < 4; ++kt) {
        int row = kt * 16 + l16;
        kofs[kt][0] = row * 64 + ((g * 8) ^ ((row & 7) << 3));
        kofs[kt][1] = row * 64 + ((32 + g * 8) ^ ((row & 7) << 3));
    }
    int pwb[4];
    #pragma unroll
    for (int kt = 0; kt < 4; ++kt)
        pwb[kt] = l16 * 64 + ((kt * 16 + g * 4) ^ ((l16 & 7) << 3));
    int prd[2];
    #pragma unroll
    for (int c = 0; c < 2; ++c)
        prd[c] = l16 * 64 + ((c * 32 + g * 8) ^ ((l16 & 7) << 3));

    f32x4 oacc[4];
    #pragma unroll
    for (int d = 0; d < 4; ++d) oacc[d] = (f32x4){0.f, 0.f, 0.f, 0.f};
    f32x4 lsum = (f32x4){0.f, 0.f, 0.f, 0.f};
    float m_run = -1e30f;

    // prologue: stage tile 0, prefetch tile 1
    bf16x8 kr0 = *(const bf16x8*)&Kg0[0];
    bf16x8 kr1 = *(const bf16x8*)&Kg1[0];
    bf16x8 vr0 = *(const bf16x8*)&Vg0[0];
    bf16x8 vr1 = *(const bf16x8*)&Vg1[0];
    *(bf16x8*)&Ks[0][wO0] = kr0;  *(bf16x8*)&Ks[0][wO1] = kr1;
    *(bf16x8*)&Vs[0][wO0] = vr0;  *(bf16x8*)&Vs[0][wO1] = vr1;
    kr0 = *(const bf16x8*)&Kg0[64 * DKn];
    kr1 = *(const bf16x8*)&Kg1[64 * DKn];
    vr0 = *(const bf16x8*)&Vg0[64];
    vr1 = *(const bf16x8*)&Vg1[64];
    __syncthreads();

    int c = 0;
    for (int t = 0; t < NT; ++t) {
        if (t < NT - 1) {
            *(bf16x8*)&Ks[c ^ 1][wO0] = kr0;  *(bf16x8*)&Ks[c ^ 1][wO1] = kr1;
            *(bf16x8*)&Vs[c ^ 1][wO0] = vr0;  *(bf16x8*)&Vs[c ^ 1][wO1] = vr1;
            int tn = (t + 2 < NT) ? t + 2 : NT - 1;
            int okt = tn * (64 * DKn), ovt = tn * 64;
            kr0 = *(const bf16x8*)&Kg0[okt];
            kr1 = *(const bf16x8*)&Kg1[okt];
            vr0 = *(const bf16x8*)&Vg0[ovt];
            vr1 = *(const bf16x8*)&Vg1[ovt];
        }

        const float* mpt = mp + t * 64;
        f32x4 mk[4];
        #pragma unroll
        for (int kt = 0; kt < 4; ++kt)
            mk[kt] = *(const f32x4*)&mpt[kt * 16 + g * 4];

        // ---- S^T = K Q^T : lane owns q=l16, kc = kt*16 + g*4 + r
        f32x4 sv[4];
        __builtin_amdgcn_s_setprio(1);
        #pragma unroll
        for (int kt = 0; kt < 4; ++kt) {
            bf16x8 kf0 = *(const bf16x8*)&Ks[c][kofs[kt][0]];
            bf16x8 kf1 = *(const bf16x8*)&Ks[c][kofs[kt][1]];
            f32x4 z = (f32x4){0.f, 0.f, 0.f, 0.f};
            z = __builtin_amdgcn_mfma_f32_16x16x32_bf16(kf0, qf0, z, 0, 0, 0);
            z = __builtin_amdgcn_mfma_f32_16x16x32_bf16(kf1, qf1, z, 0, 0, 0);
            sv[kt] = z;
        }
        __builtin_amdgcn_s_setprio(0);
        #pragma unroll
        for (int kt = 0; kt < 4; ++kt) sv[kt] += mk[kt];

        // ---- defer-max: local 16-max tree + wave check; rescale only on trigger
        float mt = fmaxf(fmaxf(sv[0][0], sv[0][1]), fmaxf(sv[0][2], sv[0][3]));
        #pragma unroll
        for (int kt = 1; kt < 4; ++kt)
            mt = fmaxf(mt, fmaxf(fmaxf(sv[kt][0], sv[kt][1]), fmaxf(sv[kt][2], sv[kt][3])));
        if (!__all(mt <= m_run + 8.0f)) {
            float mtr = fmaxf(mt, __shfl_xor(mt, 16));
            mtr = fmaxf(mtr, __shfl_xor(mtr, 32));
            float mnew = fmaxf(m_run, mtr);
            float fac  = exp2f(m_run - mnew);
            m_run = mnew;
            #pragma unroll
            for (int d = 0; d < 4; ++d) oacc[d] *= fac;
            lsum *= fac;
        }

        // ---- P = exp2(S - m), packed bf16 -> wave-private LDS
        #pragma unroll
        for (int kt = 0; kt < 4; ++kt) {
            float p0 = exp2f(sv[kt][0] - m_run), p1 = exp2f(sv[kt][1] - m_run);
            float p2 = exp2f(sv[kt][2] - m_run), p3 = exp2f(sv[kt][3] - m_run);
            *(unsigned*)&Pl[w][pwb[kt]]     = cvt_pk_bf16(p0, p1);
            *(unsigned*)&Pl[w][pwb[kt] + 2] = cvt_pk_bf16(p2, p3);
        }

        // ---- O^T += V^T P^T  and  lsum += ones * P^T  (row sums in MFMA pipe)
        __builtin_amdgcn_s_setprio(1);
        #pragma unroll
        for (int cc = 0; cc < 2; ++cc) {
            bf16x8 pf = *(const bf16x8*)&Pl[w][prd[cc]];
            lsum = __builtin_amdgcn_mfma_f32_16x16x32_bf16(ones, pf, lsum, 0, 0, 0);
            #pragma unroll
            for (int d = 0; d < 4; ++d) {
                bf16x8 vf = *(const bf16x8*)&Vs[c][kofs[d][cc]];
                oacc[d] = __builtin_amdgcn_mfma_f32_16x16x32_bf16(vf, pf, oacc[d], 0, 0, 0);
            }
        }
        __builtin_amdgcn_s_setprio(0);

        __syncthreads();
        c ^= 1;
    }

    // epilogue: lane owns q = l16 entirely; O^T rows are dk = d*16 + g*4 + r
    float inv = 1.0f / lsum[0];
    size_t mrow = (size_t)bb * Ln + q0 + w * 16 + l16;
    #pragma unroll
    for (int d = 0; d < 4; ++d) {
        uint2 pr = {cvt_pk_bf16(oacc[d][0] * inv, oacc[d][1] * inv),
                    cvt_pk_bf16(oacc[d][2] * inv, oacc[d][3] * inv)};
        *(uint2*)&Ctx[mrow * Dn + h * 64 + d * 16 + g * 4] = pr;
    }
}

// ---------------------------------------------------------------------------
// Kernel 3: output projection, bf16 MFMA. grid (Mtot/128, Dn/128), block 256.
// ---------------------------------------------------------------------------
__global__ __launch_bounds__(256) void out_proj_mfma(
    const short* __restrict__ Ctx, const float* __restrict__ W,
    const float* __restrict__ bias, float* __restrict__ Out)
{
    __shared__ short As[128 * 72];
    __shared__ short Bs[128 * 72];

    const int tid  = threadIdx.x;
    const int lane = tid & 63, w = tid >> 6;
    const int wr = w >> 1, wc = w & 1;
    const int l16 = lane & 15, g = lane >> 4;
    const int m0 = blockIdx.x * 128, n0 = blockIdx.y * 128;

    f32x4 acc[4][4];
    #pragma unroll
    for (int i = 0; i < 4; ++i)
        #pragma unroll
        for (int j = 0; j < 4; ++j)
            acc[i][j] = (f32x4){0.f, 0.f, 0.f, 0.f};

    for (int k0 = 0; k0 < Dn; k0 += 64) {
        #pragma unroll
        for (int f = 0; f < 4; ++f) {
            int lin = tid + 256 * f;
            int row = lin >> 3, c8 = lin & 7;
            bf16x8 av = *(const bf16x8*)&Ctx[(size_t)(m0 + row) * Dn + k0 + c8 * 8];
            *(bf16x8*)&As[row * 72 + c8 * 8] = av;
        }
        #pragma unroll
        for (int f = 0; f < 8; ++f) {
            int lin = tid + 256 * f;
            int row = lin >> 4, c4 = lin & 15;
            float4 wv4 = *(const float4*)&W[(size_t)(n0 + row) * Dn + k0 + c4 * 4];
            uint2 wp = {cvt_pk_bf16(wv4.x, wv4.y), cvt_pk_bf16(wv4.z, wv4.w)};
            *(uint2*)&Bs[row * 72 + c4 * 4] = wp;
        }
        __syncthreads();

        bf16x8 af[4][2], bfv[4][2];
        #pragma unroll
        for (int i = 0; i < 4; ++i)
            #pragma unroll
            for (int c = 0; c < 2; ++c)
                af[i][c] = *(const bf16x8*)&As[(wr * 64 + i * 16 + l16) * 72 + c * 32 + g * 8];
        #pragma unroll
        for (int j = 0; j < 4; ++j)
            #pragma unroll
            for (int c = 0; c < 2; ++c)
                bfv[j][c] = *(const bf16x8*)&Bs[(wc * 64 + j * 16 + l16) * 72 + c * 32 + g * 8];

        #pragma unroll
        for (int i = 0; i < 4; ++i)
            #pragma unroll
            for (int j = 0; j < 4; ++j) {
                acc[i][j] = __builtin_amdgcn_mfma_f32_16x16x32_bf16(af[i][0], bfv[j][0], acc[i][j], 0, 0, 0);
                acc[i][j] = __builtin_amdgcn_mfma_f32_16x16x32_bf16(af[i][1], bfv[j][1], acc[i][j], 0, 0, 0);
            }
        __syncthreads();
    }

    #pragma unroll
    for (int i = 0; i < 4; ++i) {
        #pragma unroll
        for (int j = 0; j < 4; ++j) {
            int n = n0 + wc * 64 + j * 16 + l16;
            float bval = bias[n];
            #pragma unroll
            for (int r = 0; r < 4; ++r) {
                int m = m0 + wr * 64 + i * 16 + g * 4 + r;
                Out[(size_t)m * Dn + n] = acc[i][j][r] + bval;
            }
        }
    }
}

// ---------------------------------------------------------------------------
extern "C" void kernel_launch(void* const* d_in, const int* in_sizes, int n_in,
                              void* d_out, int out_size, void* d_ws, size_t ws_size,
                              hipStream_t stream)
{
    (void)in_sizes; (void)n_in; (void)out_size; (void)ws_size;
    const float* q    = (const float*)d_in[0];
    const float* k    = (const float*)d_in[1];
    const float* v    = (const float*)d_in[2];
    const int*   mks  = (const int*)  d_in[3];
    const float* wq_w = (const float*)d_in[4];
    const float* wq_b = (const float*)d_in[5];
    const float* wk_w = (const float*)d_in[6];
    const float* wk_b = (const float*)d_in[7];
    const float* wv_w = (const float*)d_in[8];
    const float* wv_b = (const float*)d_in[9];
    const float* wo_w = (const float*)d_in[10];
    const float* wo_b = (const float*)d_in[11];
    float* out = (float*)d_out;

    const size_t headElems = (size_t)Bn * Hn * Ln * DKn;
    short* ws  = (short*)d_ws;
    short* Qh  = ws;
    short* Kh  = ws + headElems;
    short* Vt  = ws + 2 * headElems;
    short* Ctx = ws + 3 * headElems;
    float* maskF = (float*)(ws + 4 * headElems);

    mask_prep<<<dim3((Bn * Ln + 255) / 256), 256, 0, stream>>>(mks, maskF);

    qkv_proj_mfma<<<dim3(Mtot / 128, Dn / 128, 3), 256, 0, stream>>>(
        q, k, v, wq_w, wk_w, wv_w, wq_b, wk_b, wv_b, Qh, Kh, Vt);

    attn_mfma<<<dim3(Ln / 64, Bn * Hn), 256, 0, stream>>>(Qh, Kh, Vt, maskF, Ctx);

    out_proj_mfma<<<dim3(Mtot / 128, Dn / 128), 256, 0, stream>>>(Ctx, wo_w, wo_b, out);
}